// Round 5
// baseline (91.406 us; speedup 1.0000x reference)
//
#include <hip/hip_runtime.h>

typedef short  bf16x8  __attribute__((ext_vector_type(8)));
typedef int    int32x4 __attribute__((ext_vector_type(4)));

#define JS      13           // j-splits (grid.y)
#define STREAMS (JS * 4)     // 52 wave-streams per i-tile (stride in j-tiles)
#define TI      128          // i-points per block (4 MFMA groups per A-load)
#define DEPTH   4            // prefetch depth (buffers X/Y/Z2/W), vmcnt(3)

__device__ __forceinline__ unsigned short f2bf(float x) {
    unsigned u = __builtin_bit_cast(unsigned, x);
    u += 0x7FFF + ((u >> 16) & 1);          // RNE
    return (unsigned short)(u >> 16);
}
__device__ __forceinline__ float bf2f(unsigned short h) {
    unsigned u = ((unsigned)h) << 16;
    return __builtin_bit_cast(float, u);
}

// ---- pack padding points into MFMA-A planes + zero the output ----
// Row j (K=16 bf16): k0-2 qh | k3-5 ql | k6-8 qh | k9-11 ql | k12-13 negc h/l |
// k14-15 = 1.0,1.0 (pair B's -ha hi/lo threshold fold).
// plane0 = k0-7 (lanes 0-31), plane1 = k8-15 (lanes 32-63).
// Rows >= rows_ring REPLICATE row (j % rows_ring): the rotated streams'
// linear march (incl. DEPTH prefetch overrun) lands in valid replicas, so the
// inner loop needs no wrap logic.
__global__ __launch_bounds__(256) void dens_pack_kernel(
    const float* __restrict__ pad, uint4* __restrict__ ws,
    int* __restrict__ out, int M, int mtot, int rows_ring, int N)
{
    const int j = blockIdx.x * 256 + threadIdx.x;
    if (j < N) out[j] = 0;                      // fold output zeroing here
    if (j >= mtot) return;

    const int jsrc = j % rows_ring;             // replicate ring into overrun
    float qx = 0.f, qy = 0.f, qz = 0.f;
    float negc = -1.0e6f;                       // padded rows: s<0 -> sign -1 cancels baseline
    if (jsrc < M) {
        qx = pad[3 * jsrc]; qy = pad[3 * jsrc + 1]; qz = pad[3 * jsrc + 2];
        negc = 0.125f - 0.5f * (qx * qx + qy * qy + qz * qz);   // (r^2 - |q|^2)/2
    }
    const unsigned short xh = f2bf(qx), yh = f2bf(qy), zh = f2bf(qz);
    const unsigned short xl = f2bf(qx - bf2f(xh));
    const unsigned short yl = f2bf(qy - bf2f(yh));
    const unsigned short zl = f2bf(qz - bf2f(zh));
    const unsigned short ch = f2bf(negc);
    const unsigned short cl = f2bf(negc - bf2f(ch));

    uint4 p0, p1;
    p0.x = (unsigned)xh | ((unsigned)yh << 16);   // k0,k1
    p0.y = (unsigned)zh | ((unsigned)xl << 16);   // k2,k3
    p0.z = (unsigned)yl | ((unsigned)zl << 16);   // k4,k5
    p0.w = (unsigned)xh | ((unsigned)yh << 16);   // k6,k7
    p1.x = (unsigned)zh | ((unsigned)xl << 16);   // k8,k9
    p1.y = (unsigned)yl | ((unsigned)zl << 16);   // k10,k11
    p1.z = (unsigned)ch | ((unsigned)cl << 16);   // k12,k13
    p1.w = 0x3F803F80u;                           // k14,k15 = 1.0,1.0
    ws[j]        = p0;                            // plane0
    ws[mtot + j] = p1;                            // plane1
}

// B-frag with threshold folded into k14/k15: s = p.q + negc - ha, within <=> s>=0.
__device__ __forceinline__ void make_bfrag(const float* __restrict__ pc,
                                           int i, int N, int half, bf16x8& B)
{
    float px = 0.f, py = 0.f, pz = 0.f;
    float ha = 3.0e38f;                          // i-pad: s ~ -3e38 < 0 always
    if (i < N) {
        px = pc[3 * i]; py = pc[3 * i + 1]; pz = pc[3 * i + 2];
        ha = 0.5f * (px * px + py * py + pz * pz);   // |p|^2/2, fp32
    }
    const float nha = -ha;
    const unsigned short nhh = f2bf(nha);
    const unsigned short nhl = f2bf(nha - bf2f(nhh));   // 2-term split, err ~1e-5
    const short xh = (short)f2bf(px), yh = (short)f2bf(py), zh = (short)f2bf(pz);
    const short xl = (short)f2bf(px - bf2f((unsigned short)xh));
    const short yl = (short)f2bf(py - bf2f((unsigned short)yh));
    const short zl = (short)f2bf(pz - bf2f((unsigned short)zh));
    const short ONE = (short)0x3F80;
    const bf16x8 Blo = {xh, yh, zh, xh, yh, zh, xl, yl};                    // k0-7
    const bf16x8 Bhi = {zl, xl, yl, zl, ONE, ONE, (short)nhh, (short)nhl};  // k8-15
    B = half ? Bhi : Blo;
}

// ---- packed sign-byte gather: 4 f32 D regs -> 1 reg of 4 bytes {0x80|0x00} ----
// v_perm_b32 byte selectors (standard): 0-3 = S1.byte[sel], 4-7 = S0.byte[sel-4],
// 0x0C = 0x00. byte3 of an f32 = sign|exp[7:1]; AND 0x80 isolates the sign.
#define PACK4(D, S0, S1, S2, S3, T) \
    "v_perm_b32 " D ", " S0 ", " S1 ", %[SL]\n\t" \
    "v_perm_b32 " T ", " S2 ", " S3 ", %[SH]\n\t" \
    "v_or_b32 "  D ", " D ", " T "\n\t" \
    "v_and_b32 " D ", 0x80808080, " D "\n\t"

// bank d0 = v[32:47] -> P = v[92:95] (scratch v90)
#define PACK_D0 \
    PACK4("v92", "v32", "v33", "v34", "v35", "v90") \
    PACK4("v93", "v36", "v37", "v38", "v39", "v90") \
    PACK4("v94", "v40", "v41", "v42", "v43", "v90") \
    PACK4("v95", "v44", "v45", "v46", "v47", "v90")
// bank d1 = v[48:63] -> Q = v[112:115] (scratch v91)
#define PACK_D1 \
    PACK4("v112", "v48", "v49", "v50", "v51", "v91") \
    PACK4("v113", "v52", "v53", "v54", "v55", "v91") \
    PACK4("v114", "v56", "v57", "v58", "v59", "v91") \
    PACK4("v115", "v60", "v61", "v62", "v63", "v91")

// ONE i8 MFMA reduces a whole bank: A row r = lane&31 = local i; lane-halves
// supply k=0..15 / 16..31 -> all 32 j-indicators of the bank summed per i.
// A bytes are -128 (miss) / 0 (within); B mask 0x01 only in group-g's 8 cols
// -> four i-groups share one 16-reg i32 acc. acc = -128 * miss.
#define RED(PR, BR) \
    "v_mfma_i32_32x32x32_i8 v[96:111], " PR ", " BR ", v[96:111]\n\t"

// One visit on A-buffer AR: ONE 1KB wave-load feeds FOUR bf16 MFMAs (i-groups
// 0-3). vmcnt(3): DEPTH=4 marching buffers. Stream-phase rotation (see launch)
// de-clusters same-line L2 requests across blocks-x; loop body unchanged.
// AR reload issued only after the last bf16 MFMA reads it (in-order WAR-safe).
#define VISIT(AR) \
    "s_waitcnt vmcnt(3)\n\t" \
    "v_mfma_f32_32x32x16_bf16 v[32:47], " AR ", %[B0], v[64:79]\n\t" \
    "v_mfma_f32_32x32x16_bf16 v[48:63], " AR ", %[B1], v[64:79]\n\t" \
    "v_add_co_u32 v88, vcc, 0x6800, v88\n\t" \
    "v_addc_co_u32 v89, vcc, 0, v89, vcc\n\t" \
    "s_nop 6\n\t" \
    PACK_D0 \
    "v_mfma_f32_32x32x16_bf16 v[32:47], " AR ", %[B2], v[64:79]\n\t" \
    RED("v[92:95]", "%[R0]") \
    PACK_D1 \
    "v_mfma_f32_32x32x16_bf16 v[48:63], " AR ", %[B3], v[64:79]\n\t" \
    RED("v[112:115]", "%[R1]") \
    "global_load_dwordx4 " AR ", v[88:89], off\n\t" \
    PACK_D0 \
    PACK_D1 \
    RED("v[92:95]", "%[R2]") \
    RED("v[112:115]", "%[R3]")

// grid (157 x 13), 256 thr. 128-wide i-tile; 52 wave-streams stride j-tiles.
// Stream-phase rotation: block-x starts its tile ring at rot = bx % visits;
// marches LINEARLY through tiles rot..rot+15 (+DEPTH overrun) — the pack
// kernel's replicated overrun region makes that valid without wrap logic.
// Physical map: d0=v[32:47] d1=v[48:63] Z=v[64:79] X=v[80:83] Y=v[84:87]
//               addr=v[88:89] scratch=v90/91 P=v[92:95] acc=v[96:111]
//               Q=v[112:115] Z2=v[116:119] W=v[120:123].
// 16 visits, 4 iterations of 4 visits.
__global__ __launch_bounds__(256, 4) void dens_mfma_kernel(
    const float* __restrict__ pc,     // [N,3] pointcloud
    const char*  __restrict__ wsA,    // packed A planes ((visits+rot_ovr+DEPTH)*STREAMS tiles)
    int* __restrict__ out,            // [N] counts (pre-zeroed)
    int N, int iters, int p1off, int visits)
{
    const int lane = threadIdx.x & 63;
    const int w    = threadIdx.x >> 6;   // wave 0..3
    const int n    = lane & 31;          // output col within 32-tile = i
    const int half = lane >> 5;          // k-chunk 0/1

    const int ibase = blockIdx.x * TI;
    bf16x8 B0, B1, B2, B3;
    make_bfrag(pc, ibase + n,      N, half, B0);
    make_bfrag(pc, ibase + 32 + n, N, half, B1);
    make_bfrag(pc, ibase + 64 + n, N, half, B2);
    make_bfrag(pc, ibase + 96 + n, N, half, B3);

    // per-group column masks for the i8 reduction B operand: lane covers
    // output col (lane&31); group g owns cols 8g..8g+7 of the shared acc.
    const int gsel = n >> 3;
    const int m0 = (gsel == 0) ? 0x01010101 : 0;
    const int m1 = (gsel == 1) ? 0x01010101 : 0;
    const int m2 = (gsel == 2) ? 0x01010101 : 0;
    const int m3 = (gsel == 3) ? 0x01010101 : 0;
    const int32x4 R0 = {m0, m0, m0, m0};
    const int32x4 R1 = {m1, m1, m1, m1};
    const int32x4 R2 = {m2, m2, m2, m2};
    const int32x4 R3 = {m3, m3, m3, m3};

    const int stream = blockIdx.y * 4 + w;          // 0..51
    const int rot    = blockIdx.x % visits;         // stream-phase rotation
    const unsigned long long ax =
        (unsigned long long)(wsA + (half ? p1off : 0) + n * 16
                             + (size_t)stream * 512
                             + (size_t)rot * 0x6800);   // start at tile 'rot'
    const unsigned xlo = (unsigned)ax, xhi = (unsigned)(ax >> 32);

    int it = iters;
    int a0, a1, a2, a3, a4, a5, a6, a7, a8, a9, a10, a11, a12, a13, a14, a15;

    asm volatile(
        // ---- preamble: marching addr, Z=0 bank, acc=0, DEPTH=4 prefetches ----
        "v_mov_b32 v88, %[xlo]\n\t"
        "v_mov_b32 v89, %[xhi]\n\t"
        "v_mov_b32 v64, 0\n\t" "v_mov_b32 v65, 0\n\t"
        "v_mov_b32 v66, 0\n\t" "v_mov_b32 v67, 0\n\t"
        "v_mov_b32 v68, 0\n\t" "v_mov_b32 v69, 0\n\t"
        "v_mov_b32 v70, 0\n\t" "v_mov_b32 v71, 0\n\t"
        "v_mov_b32 v72, 0\n\t" "v_mov_b32 v73, 0\n\t"
        "v_mov_b32 v74, 0\n\t" "v_mov_b32 v75, 0\n\t"
        "v_mov_b32 v76, 0\n\t" "v_mov_b32 v77, 0\n\t"
        "v_mov_b32 v78, 0\n\t" "v_mov_b32 v79, 0\n\t"
        "v_mov_b32 v96, 0\n\t"  "v_mov_b32 v97, 0\n\t"
        "v_mov_b32 v98, 0\n\t"  "v_mov_b32 v99, 0\n\t"
        "v_mov_b32 v100, 0\n\t" "v_mov_b32 v101, 0\n\t"
        "v_mov_b32 v102, 0\n\t" "v_mov_b32 v103, 0\n\t"
        "v_mov_b32 v104, 0\n\t" "v_mov_b32 v105, 0\n\t"
        "v_mov_b32 v106, 0\n\t" "v_mov_b32 v107, 0\n\t"
        "v_mov_b32 v108, 0\n\t" "v_mov_b32 v109, 0\n\t"
        "v_mov_b32 v110, 0\n\t" "v_mov_b32 v111, 0\n\t"
        "global_load_dwordx4 v[80:83], v[88:89], off\n\t"
        "v_add_co_u32 v88, vcc, 0x6800, v88\n\t"
        "v_addc_co_u32 v89, vcc, 0, v89, vcc\n\t"
        "global_load_dwordx4 v[84:87], v[88:89], off\n\t"
        "v_add_co_u32 v88, vcc, 0x6800, v88\n\t"
        "v_addc_co_u32 v89, vcc, 0, v89, vcc\n\t"
        "global_load_dwordx4 v[116:119], v[88:89], off\n\t"
        "v_add_co_u32 v88, vcc, 0x6800, v88\n\t"
        "v_addc_co_u32 v89, vcc, 0, v89, vcc\n\t"
        "global_load_dwordx4 v[120:123], v[88:89], off\n\t"
        "Ldens%=:\n\t"
        VISIT("v[80:83]")
        VISIT("v[84:87]")
        VISIT("v[116:119]")
        VISIT("v[120:123]")
        "s_sub_u32 %[it], %[it], 1\n\t"
        "s_cmp_lg_u32 %[it], 0\n\t"
        "s_cbranch_scc1 Ldens%=\n\t"
        // drain in-flight loads: they write clobbered regs the C++ epilogue
        // may reuse; then drain MFMA pipe before VALU reads acc.
        "s_waitcnt vmcnt(0)\n\t"
        "s_nop 7\n\t" "s_nop 7\n\t" "s_nop 7\n\t"
        "v_mov_b32 %[a0],  v96\n\t"  "v_mov_b32 %[a1],  v97\n\t"
        "v_mov_b32 %[a2],  v98\n\t"  "v_mov_b32 %[a3],  v99\n\t"
        "v_mov_b32 %[a4],  v100\n\t" "v_mov_b32 %[a5],  v101\n\t"
        "v_mov_b32 %[a6],  v102\n\t" "v_mov_b32 %[a7],  v103\n\t"
        "v_mov_b32 %[a8],  v104\n\t" "v_mov_b32 %[a9],  v105\n\t"
        "v_mov_b32 %[a10], v106\n\t" "v_mov_b32 %[a11], v107\n\t"
        "v_mov_b32 %[a12], v108\n\t" "v_mov_b32 %[a13], v109\n\t"
        "v_mov_b32 %[a14], v110\n\t" "v_mov_b32 %[a15], v111\n\t"
        : [a0]"=v"(a0),   [a1]"=v"(a1),   [a2]"=v"(a2),   [a3]"=v"(a3),
          [a4]"=v"(a4),   [a5]"=v"(a5),   [a6]"=v"(a6),   [a7]"=v"(a7),
          [a8]"=v"(a8),   [a9]"=v"(a9),   [a10]"=v"(a10), [a11]"=v"(a11),
          [a12]"=v"(a12), [a13]"=v"(a13), [a14]"=v"(a14), [a15]"=v"(a15),
          [it]"+s"(it)
        : [B0]"v"(B0), [B1]"v"(B1), [B2]"v"(B2), [B3]"v"(B3),
          [R0]"v"(R0), [R1]"v"(R1), [R2]"v"(R2), [R3]"v"(R3),
          [SL]"s"(0x0C0C0703u), [SH]"s"(0x07030C0Cu),
          [xlo]"v"(xlo), [xhi]"v"(xhi)
        : "vcc", "scc", "memory",
          "v32","v33","v34","v35","v36","v37","v38","v39",
          "v40","v41","v42","v43","v44","v45","v46","v47",
          "v48","v49","v50","v51","v52","v53","v54","v55",
          "v56","v57","v58","v59","v60","v61","v62","v63",
          "v64","v65","v66","v67","v68","v69","v70","v71",
          "v72","v73","v74","v75","v76","v77","v78","v79",
          "v80","v81","v82","v83","v84","v85","v86","v87",
          "v88","v89","v90","v91","v92","v93","v94","v95",
          "v96","v97","v98","v99","v100","v101","v102","v103",
          "v104","v105","v106","v107","v108","v109","v110","v111",
          "v112","v113","v114","v115","v116","v117","v118","v119",
          "v120","v121","v122","v123");

    // acc D-layout (32x32 i32): col = lane&31 (group g = col>>3, value
    // replicated across the 8 cols of its range), row = (q&3)+8*(q>>2)+4*half
    // = local i. acc = -128 * (#not-within) over this wave's 32*visits j's
    // -> per-i count for this wave = 32*visits + (acc >> 7).
    const int base = 32 * visits;
    __shared__ int red[4][TI];
    if ((lane & 7) == 0) {                       // one writer per (group,half)
        const int g   = n >> 3;
        const int hi4 = half << 2;               // +4 rows for upper lane-half
        int* rw = &red[w][32 * g];
        rw[ 0 + hi4] = base + (a0  >> 7);
        rw[ 1 + hi4] = base + (a1  >> 7);
        rw[ 2 + hi4] = base + (a2  >> 7);
        rw[ 3 + hi4] = base + (a3  >> 7);
        rw[ 8 + hi4] = base + (a4  >> 7);
        rw[ 9 + hi4] = base + (a5  >> 7);
        rw[10 + hi4] = base + (a6  >> 7);
        rw[11 + hi4] = base + (a7  >> 7);
        rw[16 + hi4] = base + (a8  >> 7);
        rw[17 + hi4] = base + (a9  >> 7);
        rw[18 + hi4] = base + (a10 >> 7);
        rw[19 + hi4] = base + (a11 >> 7);
        rw[24 + hi4] = base + (a12 >> 7);
        rw[25 + hi4] = base + (a13 >> 7);
        rw[26 + hi4] = base + (a14 >> 7);
        rw[27 + hi4] = base + (a15 >> 7);
    }
    __syncthreads();
    if (threadIdx.x < TI) {
        const int ii = ibase + threadIdx.x;
        if (ii < N) {
            const int s = red[0][threadIdx.x] + red[1][threadIdx.x] +
                          red[2][threadIdx.x] + red[3][threadIdx.x];
            atomicAdd(&out[ii], s);
        }
    }
}

extern "C" void kernel_launch(void* const* d_in, const int* in_sizes, int n_in,
                              void* d_out, int out_size, void* d_ws, size_t ws_size,
                              hipStream_t stream) {
    const float* pc  = (const float*)d_in[0];   // [N,3] pointcloud
    const float* pad = (const float*)d_in[1];   // [M,3] pointcloud_padding
    int* out = (int*)d_out;

    const int N = in_sizes[0] / 3;              // 20000
    const int M = in_sizes[1] / 3;              // 25000
    const int jt = (M + 31) / 32;               // 782 j-tiles
    int visits = (jt + STREAMS - 1) / STREAMS;  // 16
    visits = (visits + 3) & ~3;                 // 4-visit unrolled body
    // ring (visits tiles) + replicated overrun for rotation (visits-1) and
    // DEPTH prefetch: rotated waves march linearly, never wrap.
    const int jtp  = visits + (visits - 1) + DEPTH;     // 35 tile-tiers
    const int rows_ring = visits * STREAMS * 32;        // 26624 rows in ring
    const int mtot = jtp * STREAMS * 32;                // 58240 rows (~1.86 MB)

    dens_pack_kernel<<<(mtot + 255) / 256, 256, 0, stream>>>(
        pad, (uint4*)d_ws, out, M, mtot, rows_ring, N);

    dim3 grid((N + TI - 1) / TI, JS);           // 157 x 13
    dens_mfma_kernel<<<grid, 256, 0, stream>>>(
        pc, (const char*)d_ws, out, N, visits / 4, mtot * 16, visits);
}

// Round 7
// 90.338 us; speedup vs baseline: 1.0118x; 1.0118x over previous
//
#include <hip/hip_runtime.h>

typedef short  bf16x8  __attribute__((ext_vector_type(8)));
typedef int    int32x4 __attribute__((ext_vector_type(4)));

#define JS      13           // j-splits (grid.y)
#define STREAMS (JS * 4)     // 52 wave-streams per i-tile (stride in j-tiles)
#define TI      128          // i-points per block (4 MFMA groups per A-load)
#define DEPTH   2            // prefetch depth (buffers X/Y), vmcnt(1)

__device__ __forceinline__ unsigned short f2bf(float x) {
    unsigned u = __builtin_bit_cast(unsigned, x);
    u += 0x7FFF + ((u >> 16) & 1);          // RNE
    return (unsigned short)(u >> 16);
}
__device__ __forceinline__ float bf2f(unsigned short h) {
    unsigned u = ((unsigned)h) << 16;
    return __builtin_bit_cast(float, u);
}

// ---- pack padding points into MFMA-A planes + zero the output ----
// Row j (K=16 bf16): k0-2 qh | k3-5 ql | k6-8 qh | k9-11 ql | k12-13 negc h/l |
// k14-15 = 1.0,1.0 (pair B's -ha hi/lo threshold fold).
// plane0 = k0-7 (lanes 0-31), plane1 = k8-15 (lanes 32-63).
__global__ __launch_bounds__(256) void dens_pack_kernel(
    const float* __restrict__ pad, uint4* __restrict__ ws,
    int* __restrict__ out, int M, int mtot, int N)
{
    const int j = blockIdx.x * 256 + threadIdx.x;
    if (j < N) out[j] = 0;                      // fold output zeroing here
    if (j >= mtot) return;

    float qx = 0.f, qy = 0.f, qz = 0.f;
    float negc = -1.0e6f;                       // padded rows: s<0 -> sign -1 cancels baseline
    if (j < M) {
        qx = pad[3 * j]; qy = pad[3 * j + 1]; qz = pad[3 * j + 2];
        negc = 0.125f - 0.5f * (qx * qx + qy * qy + qz * qz);   // (r^2 - |q|^2)/2
    }
    const unsigned short xh = f2bf(qx), yh = f2bf(qy), zh = f2bf(qz);
    const unsigned short xl = f2bf(qx - bf2f(xh));
    const unsigned short yl = f2bf(qy - bf2f(yh));
    const unsigned short zl = f2bf(qz - bf2f(zh));
    const unsigned short ch = f2bf(negc);
    const unsigned short cl = f2bf(negc - bf2f(ch));

    uint4 p0, p1;
    p0.x = (unsigned)xh | ((unsigned)yh << 16);   // k0,k1
    p0.y = (unsigned)zh | ((unsigned)xl << 16);   // k2,k3
    p0.z = (unsigned)yl | ((unsigned)zl << 16);   // k4,k5
    p0.w = (unsigned)xh | ((unsigned)yh << 16);   // k6,k7
    p1.x = (unsigned)zh | ((unsigned)xl << 16);   // k8,k9
    p1.y = (unsigned)yl | ((unsigned)zl << 16);   // k10,k11
    p1.z = (unsigned)ch | ((unsigned)cl << 16);   // k12,k13
    p1.w = 0x3F803F80u;                           // k14,k15 = 1.0,1.0
    ws[j]        = p0;                            // plane0
    ws[mtot + j] = p1;                            // plane1
}

// B-frag with threshold folded into k14/k15: s = p.q + negc - ha, within <=> s>=0.
__device__ __forceinline__ void make_bfrag(const float* __restrict__ pc,
                                           int i, int N, int half, bf16x8& B)
{
    float px = 0.f, py = 0.f, pz = 0.f;
    float ha = 3.0e38f;                          // i-pad: s ~ -3e38 < 0 always
    if (i < N) {
        px = pc[3 * i]; py = pc[3 * i + 1]; pz = pc[3 * i + 2];
        ha = 0.5f * (px * px + py * py + pz * pz);   // |p|^2/2, fp32
    }
    const float nha = -ha;
    const unsigned short nhh = f2bf(nha);
    const unsigned short nhl = f2bf(nha - bf2f(nhh));   // 2-term split, err ~1e-5
    const short xh = (short)f2bf(px), yh = (short)f2bf(py), zh = (short)f2bf(pz);
    const short xl = (short)f2bf(px - bf2f((unsigned short)xh));
    const short yl = (short)f2bf(py - bf2f((unsigned short)yh));
    const short zl = (short)f2bf(pz - bf2f((unsigned short)zh));
    const short ONE = (short)0x3F80;
    const bf16x8 Blo = {xh, yh, zh, xh, yh, zh, xl, yl};                    // k0-7
    const bf16x8 Bhi = {zl, xl, yl, zl, ONE, ONE, (short)nhh, (short)nhl};  // k8-15
    B = half ? Bhi : Blo;
}

// ---- packed sign-byte gather: 4 f32 D regs -> 1 reg of 4 bytes {0x80|0x00} ----
// v_perm_b32 byte selectors (standard): 0-3 = S1.byte[sel], 4-7 = S0.byte[sel-4],
// 0x0C = 0x00. byte3 of an f32 = sign|exp[7:1]; AND 0x80 isolates the sign.
#define PACK4(D, S0, S1, S2, S3, T) \
    "v_perm_b32 " D ", " S0 ", " S1 ", %[SL]\n\t" \
    "v_perm_b32 " T ", " S2 ", " S3 ", %[SH]\n\t" \
    "v_or_b32 "  D ", " D ", " T "\n\t" \
    "v_and_b32 " D ", 0x80808080, " D "\n\t"

// bank d0 = v[48:63] -> P = v[120:123] (scratch v46)
#define PACK_D0 \
    PACK4("v120", "v48", "v49", "v50", "v51", "v46") \
    PACK4("v121", "v52", "v53", "v54", "v55", "v46") \
    PACK4("v122", "v56", "v57", "v58", "v59", "v46") \
    PACK4("v123", "v60", "v61", "v62", "v63", "v46")
// bank d1 = v[64:79] -> Q = v[124:127] (scratch v47)
#define PACK_D1 \
    PACK4("v124", "v64", "v65", "v66", "v67", "v47") \
    PACK4("v125", "v68", "v69", "v70", "v71", "v47") \
    PACK4("v126", "v72", "v73", "v74", "v75", "v47") \
    PACK4("v127", "v76", "v77", "v78", "v79", "v47")

// ONE i8 MFMA reduces a whole packed bank: A row r = lane&31 = local i;
// lane-halves supply k=0..15 / 16..31 -> all 32 j-indicators summed per i.
// A bytes are -128 (miss) / 0 (within); B mask 0x01 only in group-g's 8 cols
// -> four i-groups share one 16-reg i32 acc. acc = -128 * miss.
#define RED(PR, BR) \
    "v_mfma_i32_32x32x32_i8 v[96:111], " PR ", " BR ", v[96:111]\n\t"

// One visit on A-buffer AR: ONE 1KB wave-load feeds FOUR bf16 MFMAs (i-groups
// 0-3). EXACT R2-proven instruction sequence (3x harness-verified), registers
// renumbered into a v44-v127 fixed map so total allocation fits 128 VGPR ->
// 4 waves/SIMD (R2's v32-v115 map forced operands above v115 -> 224 regs,
// 2 waves/SIMD). AR reload issued only after the last bf16 MFMA reads it.
#define VISIT(AR) \
    "s_waitcnt vmcnt(1)\n\t" \
    "v_mfma_f32_32x32x16_bf16 v[48:63], " AR ", %[B0], v[80:95]\n\t" \
    "v_mfma_f32_32x32x16_bf16 v[64:79], " AR ", %[B1], v[80:95]\n\t" \
    "v_add_co_u32 v44, vcc, 0x6800, v44\n\t" \
    "v_addc_co_u32 v45, vcc, 0, v45, vcc\n\t" \
    "s_nop 6\n\t" \
    PACK_D0 \
    "v_mfma_f32_32x32x16_bf16 v[48:63], " AR ", %[B2], v[80:95]\n\t" \
    RED("v[120:123]", "%[R0]") \
    PACK_D1 \
    "v_mfma_f32_32x32x16_bf16 v[64:79], " AR ", %[B3], v[80:95]\n\t" \
    RED("v[124:127]", "%[R1]") \
    "global_load_dwordx4 " AR ", v[44:45], off\n\t" \
    PACK_D0 \
    PACK_D1 \
    RED("v[120:123]", "%[R2]") \
    RED("v[124:127]", "%[R3]")

// grid (157 x 13), 256 thr. 128-wide i-tile; 52 wave-streams stride j-tiles.
// Fixed map (84 regs, v44-v127; 16-reg MFMA tuples 16-aligned):
//   addr=v[44:45] scratch=v46,v47 d0=v[48:63] d1=v[64:79] Z=v[80:95]
//   acc=v[96:111] X=v[112:115] Y=v[116:119] P=v[120:123] Q=v[124:127]
// Compiler region v0-v43 (44 regs) holds B0-3 (4x4), R0-3 (4x4), xlo/xhi,
// temps -> total <=128 VGPR under __launch_bounds__(256,4).
// 16 visits, 8 iterations of 2 visits.
__global__ __launch_bounds__(256, 4) void dens_mfma_kernel(
    const float* __restrict__ pc,     // [N,3] pointcloud
    const char*  __restrict__ wsA,    // packed A planes ((visits+DEPTH)*STREAMS tiles)
    int* __restrict__ out,            // [N] counts (pre-zeroed)
    int N, int iters, int p1off, int visits)
{
    const int lane = threadIdx.x & 63;
    const int w    = threadIdx.x >> 6;   // wave 0..3
    const int n    = lane & 31;          // output col within 32-tile = i
    const int half = lane >> 5;          // k-chunk 0/1

    const int ibase = blockIdx.x * TI;
    bf16x8 B0, B1, B2, B3;
    make_bfrag(pc, ibase + n,      N, half, B0);
    make_bfrag(pc, ibase + 32 + n, N, half, B1);
    make_bfrag(pc, ibase + 64 + n, N, half, B2);
    make_bfrag(pc, ibase + 96 + n, N, half, B3);

    // per-group column masks for the i8 reduction B operand: lane covers
    // output col (lane&31); group g owns cols 8g..8g+7 of the shared acc.
    const int gsel = n >> 3;
    const int m0 = (gsel == 0) ? 0x01010101 : 0;
    const int m1 = (gsel == 1) ? 0x01010101 : 0;
    const int m2 = (gsel == 2) ? 0x01010101 : 0;
    const int m3 = (gsel == 3) ? 0x01010101 : 0;
    const int32x4 R0 = {m0, m0, m0, m0};
    const int32x4 R1 = {m1, m1, m1, m1};
    const int32x4 R2 = {m2, m2, m2, m2};
    const int32x4 R3 = {m3, m3, m3, m3};

    const int stream = blockIdx.y * 4 + w;          // 0..51
    const unsigned long long ax =
        (unsigned long long)(wsA + (half ? p1off : 0) + n * 16 + (size_t)stream * 512);
    const unsigned xlo = (unsigned)ax, xhi = (unsigned)(ax >> 32);

    int it = iters;
    int a0, a1, a2, a3, a4, a5, a6, a7, a8, a9, a10, a11, a12, a13, a14, a15;

    asm volatile(
        // ---- preamble: marching addr, Z=0 bank, acc=0, DEPTH=2 prefetches ----
        "v_mov_b32 v44, %[xlo]\n\t"
        "v_mov_b32 v45, %[xhi]\n\t"
        "v_mov_b32 v80, 0\n\t" "v_mov_b32 v81, 0\n\t"
        "v_mov_b32 v82, 0\n\t" "v_mov_b32 v83, 0\n\t"
        "v_mov_b32 v84, 0\n\t" "v_mov_b32 v85, 0\n\t"
        "v_mov_b32 v86, 0\n\t" "v_mov_b32 v87, 0\n\t"
        "v_mov_b32 v88, 0\n\t" "v_mov_b32 v89, 0\n\t"
        "v_mov_b32 v90, 0\n\t" "v_mov_b32 v91, 0\n\t"
        "v_mov_b32 v92, 0\n\t" "v_mov_b32 v93, 0\n\t"
        "v_mov_b32 v94, 0\n\t" "v_mov_b32 v95, 0\n\t"
        "v_mov_b32 v96, 0\n\t"  "v_mov_b32 v97, 0\n\t"
        "v_mov_b32 v98, 0\n\t"  "v_mov_b32 v99, 0\n\t"
        "v_mov_b32 v100, 0\n\t" "v_mov_b32 v101, 0\n\t"
        "v_mov_b32 v102, 0\n\t" "v_mov_b32 v103, 0\n\t"
        "v_mov_b32 v104, 0\n\t" "v_mov_b32 v105, 0\n\t"
        "v_mov_b32 v106, 0\n\t" "v_mov_b32 v107, 0\n\t"
        "v_mov_b32 v108, 0\n\t" "v_mov_b32 v109, 0\n\t"
        "v_mov_b32 v110, 0\n\t" "v_mov_b32 v111, 0\n\t"
        "global_load_dwordx4 v[112:115], v[44:45], off\n\t"
        "v_add_co_u32 v44, vcc, 0x6800, v44\n\t"
        "v_addc_co_u32 v45, vcc, 0, v45, vcc\n\t"
        "global_load_dwordx4 v[116:119], v[44:45], off\n\t"
        "Ldens%=:\n\t"
        VISIT("v[112:115]")
        VISIT("v[116:119]")
        "s_sub_u32 %[it], %[it], 1\n\t"
        "s_cmp_lg_u32 %[it], 0\n\t"
        "s_cbranch_scc1 Ldens%=\n\t"
        // drain in-flight loads (they write fixed-map regs the C++ epilogue
        // may reuse), then drain MFMA pipe before VALU reads acc.
        "s_waitcnt vmcnt(0)\n\t"
        "s_nop 7\n\t" "s_nop 7\n\t" "s_nop 7\n\t"
        "v_mov_b32 %[a0],  v96\n\t"  "v_mov_b32 %[a1],  v97\n\t"
        "v_mov_b32 %[a2],  v98\n\t"  "v_mov_b32 %[a3],  v99\n\t"
        "v_mov_b32 %[a4],  v100\n\t" "v_mov_b32 %[a5],  v101\n\t"
        "v_mov_b32 %[a6],  v102\n\t" "v_mov_b32 %[a7],  v103\n\t"
        "v_mov_b32 %[a8],  v104\n\t" "v_mov_b32 %[a9],  v105\n\t"
        "v_mov_b32 %[a10], v106\n\t" "v_mov_b32 %[a11], v107\n\t"
        "v_mov_b32 %[a12], v108\n\t" "v_mov_b32 %[a13], v109\n\t"
        "v_mov_b32 %[a14], v110\n\t" "v_mov_b32 %[a15], v111\n\t"
        : [a0]"=v"(a0),   [a1]"=v"(a1),   [a2]"=v"(a2),   [a3]"=v"(a3),
          [a4]"=v"(a4),   [a5]"=v"(a5),   [a6]"=v"(a6),   [a7]"=v"(a7),
          [a8]"=v"(a8),   [a9]"=v"(a9),   [a10]"=v"(a10), [a11]"=v"(a11),
          [a12]"=v"(a12), [a13]"=v"(a13), [a14]"=v"(a14), [a15]"=v"(a15),
          [it]"+s"(it)
        : [B0]"v"(B0), [B1]"v"(B1), [B2]"v"(B2), [B3]"v"(B3),
          [R0]"v"(R0), [R1]"v"(R1), [R2]"v"(R2), [R3]"v"(R3),
          [SL]"s"(0x0C0C0703u), [SH]"s"(0x07030C0Cu),
          [xlo]"v"(xlo), [xhi]"v"(xhi)
        : "vcc", "scc", "memory",
          "v44","v45","v46","v47",
          "v48","v49","v50","v51","v52","v53","v54","v55",
          "v56","v57","v58","v59","v60","v61","v62","v63",
          "v64","v65","v66","v67","v68","v69","v70","v71",
          "v72","v73","v74","v75","v76","v77","v78","v79",
          "v80","v81","v82","v83","v84","v85","v86","v87",
          "v88","v89","v90","v91","v92","v93","v94","v95",
          "v96","v97","v98","v99","v100","v101","v102","v103",
          "v104","v105","v106","v107","v108","v109","v110","v111",
          "v112","v113","v114","v115","v116","v117","v118","v119",
          "v120","v121","v122","v123","v124","v125","v126","v127");

    // acc D-layout (32x32 i32): col = lane&31 (group g = col>>3, value
    // replicated across the 8 cols of its range), row = (q&3)+8*(q>>2)+4*half
    // = local i. acc = -128 * (#not-within) over this wave's 32*visits j's
    // -> per-i count for this wave = 32*visits + (acc >> 7).
    const int base = 32 * visits;
    __shared__ int red[4][TI];
    if ((lane & 7) == 0) {                       // one writer per (group,half)
        const int g   = n >> 3;
        const int hi4 = half << 2;               // +4 rows for upper lane-half
        int* rw = &red[w][32 * g];
        rw[ 0 + hi4] = base + (a0  >> 7);
        rw[ 1 + hi4] = base + (a1  >> 7);
        rw[ 2 + hi4] = base + (a2  >> 7);
        rw[ 3 + hi4] = base + (a3  >> 7);
        rw[ 8 + hi4] = base + (a4  >> 7);
        rw[ 9 + hi4] = base + (a5  >> 7);
        rw[10 + hi4] = base + (a6  >> 7);
        rw[11 + hi4] = base + (a7  >> 7);
        rw[16 + hi4] = base + (a8  >> 7);
        rw[17 + hi4] = base + (a9  >> 7);
        rw[18 + hi4] = base + (a10 >> 7);
        rw[19 + hi4] = base + (a11 >> 7);
        rw[24 + hi4] = base + (a12 >> 7);
        rw[25 + hi4] = base + (a13 >> 7);
        rw[26 + hi4] = base + (a14 >> 7);
        rw[27 + hi4] = base + (a15 >> 7);
    }
    __syncthreads();
    if (threadIdx.x < TI) {
        const int ii = ibase + threadIdx.x;
        if (ii < N) {
            const int s = red[0][threadIdx.x] + red[1][threadIdx.x] +
                          red[2][threadIdx.x] + red[3][threadIdx.x];
            atomicAdd(&out[ii], s);
        }
    }
}

extern "C" void kernel_launch(void* const* d_in, const int* in_sizes, int n_in,
                              void* d_out, int out_size, void* d_ws, size_t ws_size,
                              hipStream_t stream) {
    const float* pc  = (const float*)d_in[0];   // [N,3] pointcloud
    const float* pad = (const float*)d_in[1];   // [M,3] pointcloud_padding
    int* out = (int*)d_out;

    const int N = in_sizes[0] / 3;              // 20000
    const int M = in_sizes[1] / 3;              // 25000
    const int jt = (M + 31) / 32;               // 782 j-tiles
    int visits = (jt + STREAMS - 1) / STREAMS;  // 16
    if (visits & 1) visits++;                   // 2-visit unrolled body
    const int jtp  = (visits + DEPTH) * STREAMS;    // 936 tiles incl. prefetch overrun
    const int mtot = jtp * 32;                  // 29952 rows (~958 KB in ws)

    dens_pack_kernel<<<(mtot + 255) / 256, 256, 0, stream>>>(
        pad, (uint4*)d_ws, out, M, mtot, N);

    dim3 grid((N + TI - 1) / TI, JS);           // 157 x 13
    dens_mfma_kernel<<<grid, 256, 0, stream>>>(
        pc, (const char*)d_ws, out, N, visits / 2, mtot * 16, visits);
}

// Round 9
// 81.871 us; speedup vs baseline: 1.1165x; 1.1034x over previous
//
#include <hip/hip_runtime.h>

typedef short  bf16x8   __attribute__((ext_vector_type(8)));
typedef int    int32x4  __attribute__((ext_vector_type(4)));
typedef int    int32x16 __attribute__((ext_vector_type(16)));
typedef float  f32x16   __attribute__((ext_vector_type(16)));

#define JS      13           // j-splits (grid.y)
#define STREAMS (JS * 4)     // 52 wave-streams per i-tile (stride in j-tiles)
#define TI      128          // i-points per block (4 MFMA groups per A-load)
#define DEPTH   2            // prefetch depth (buffers X/Y)

__device__ __forceinline__ unsigned short f2bf(float x) {
    unsigned u = __builtin_bit_cast(unsigned, x);
    u += 0x7FFF + ((u >> 16) & 1);          // RNE
    return (unsigned short)(u >> 16);
}
__device__ __forceinline__ float bf2f(unsigned short h) {
    unsigned u = ((unsigned)h) << 16;
    return __builtin_bit_cast(float, u);
}

// ---- pack padding points into MFMA-A planes + zero the output ----
// Row j (K=16 bf16): k0-2 qh | k3-5 ql | k6-8 qh | k9-11 ql | k12-13 negc h/l |
// k14-15 = 1.0,1.0 (pair B's -ha hi/lo threshold fold).
// plane0 = k0-7 (lanes 0-31), plane1 = k8-15 (lanes 32-63).
__global__ __launch_bounds__(256) void dens_pack_kernel(
    const float* __restrict__ pad, uint4* __restrict__ ws,
    int* __restrict__ out, int M, int mtot, int N)
{
    const int j = blockIdx.x * 256 + threadIdx.x;
    if (j < N) out[j] = 0;                      // fold output zeroing here
    if (j >= mtot) return;

    float qx = 0.f, qy = 0.f, qz = 0.f;
    float negc = -1.0e6f;                       // padded rows: s<0 -> sign -1 cancels baseline
    if (j < M) {
        qx = pad[3 * j]; qy = pad[3 * j + 1]; qz = pad[3 * j + 2];
        negc = 0.125f - 0.5f * (qx * qx + qy * qy + qz * qz);   // (r^2 - |q|^2)/2
    }
    const unsigned short xh = f2bf(qx), yh = f2bf(qy), zh = f2bf(qz);
    const unsigned short xl = f2bf(qx - bf2f(xh));
    const unsigned short yl = f2bf(qy - bf2f(yh));
    const unsigned short zl = f2bf(qz - bf2f(zh));
    const unsigned short ch = f2bf(negc);
    const unsigned short cl = f2bf(negc - bf2f(ch));

    uint4 p0, p1;
    p0.x = (unsigned)xh | ((unsigned)yh << 16);   // k0,k1
    p0.y = (unsigned)zh | ((unsigned)xl << 16);   // k2,k3
    p0.z = (unsigned)yl | ((unsigned)zl << 16);   // k4,k5
    p0.w = (unsigned)xh | ((unsigned)yh << 16);   // k6,k7
    p1.x = (unsigned)zh | ((unsigned)xl << 16);   // k8,k9
    p1.y = (unsigned)yl | ((unsigned)zl << 16);   // k10,k11
    p1.z = (unsigned)ch | ((unsigned)cl << 16);   // k12,k13
    p1.w = 0x3F803F80u;                           // k14,k15 = 1.0,1.0
    ws[j]        = p0;                            // plane0
    ws[mtot + j] = p1;                            // plane1
}

// B-frag with threshold folded into k14/k15: s = p.q + negc - ha, within <=> s>=0.
__device__ __forceinline__ void make_bfrag(const float* __restrict__ pc,
                                           int i, int N, int half, bf16x8& B)
{
    float px = 0.f, py = 0.f, pz = 0.f;
    float ha = 3.0e38f;                          // i-pad: s ~ -3e38 < 0 always
    if (i < N) {
        px = pc[3 * i]; py = pc[3 * i + 1]; pz = pc[3 * i + 2];
        ha = 0.5f * (px * px + py * py + pz * pz);   // |p|^2/2, fp32
    }
    const float nha = -ha;
    const unsigned short nhh = f2bf(nha);
    const unsigned short nhl = f2bf(nha - bf2f(nhh));   // 2-term split, err ~1e-5
    const short xh = (short)f2bf(px), yh = (short)f2bf(py), zh = (short)f2bf(pz);
    const short xl = (short)f2bf(px - bf2f((unsigned short)xh));
    const short yl = (short)f2bf(py - bf2f((unsigned short)yh));
    const short zl = (short)f2bf(pz - bf2f((unsigned short)zh));
    const short ONE = (short)0x3F80;
    const bf16x8 Blo = {xh, yh, zh, xh, yh, zh, xl, yl};                    // k0-7
    const bf16x8 Bhi = {zl, xl, yl, zl, ONE, ONE, (short)nhh, (short)nhl};  // k8-15
    B = half ? Bhi : Blo;
}

// ---- packed sign-byte gather: 4 f32 D values -> 1 word of 4 bytes {0x80|0} ----
// v_perm_b32: D.byte[i] = sel.byte[i] in 0-3 -> S1.byte[sel], 4-7 -> S0.byte[sel-4],
// 0x0C -> 0x00. byte3 of an f32 = sign|exp[7:1]; AND 0x80 isolates the sign.
// Byte order within the word is irrelevant (all 32 indicators are summed).
__device__ __forceinline__ unsigned pack4(float f0, float f1, float f2, float f3) {
    const unsigned u0 = __builtin_bit_cast(unsigned, f0);
    const unsigned u1 = __builtin_bit_cast(unsigned, f1);
    const unsigned u2 = __builtin_bit_cast(unsigned, f2);
    const unsigned u3 = __builtin_bit_cast(unsigned, f3);
    const unsigned lo = __builtin_amdgcn_perm(u0, u1, 0x0C0C0703u);  // {u1.b3,u0.b3,0,0}
    const unsigned hi = __builtin_amdgcn_perm(u2, u3, 0x07030C0Cu);  // {0,0,u3.b3,u2.b3}
    return (lo | hi) & 0x80808080u;
}

// ONE i8 MFMA reduces a packed D bank: A row r = lane&31 = local i; lane-halves
// supply k=0..15 / 16..31 -> all 32 j-indicators summed per i. A bytes are
// -128 (miss) / 0 (within); B mask 0x01 only in group-g's 8 cols -> four
// i-groups share one 16-reg i32 acc. acc = -128 * miss.
__device__ __forceinline__ int32x16 red_group(const f32x16 d, int32x4 m, int32x16 acc) {
    int32x4 P;
    P[0] = (int)pack4(d[0],  d[1],  d[2],  d[3]);
    P[1] = (int)pack4(d[4],  d[5],  d[6],  d[7]);
    P[2] = (int)pack4(d[8],  d[9],  d[10], d[11]);
    P[3] = (int)pack4(d[12], d[13], d[14], d[15]);
    return __builtin_amdgcn_mfma_i32_32x32x32_i8(P, m, acc, 0, 0, 0);
}

// grid (157 x 13), 256 thr. 128-wide i-tile; 52 wave-streams stride j-tiles.
// Same algorithm/layout as the asm version (R2-proven numerics), but
// COMPILER-SCHEDULED: intrinsics only, no fixed register map, no hand nops.
// __launch_bounds__(256,4) caps allocation at 128 VGPR -> 4 waves/SIMD target
// (est. demand ~100-120: acc16 + z16 + B16 + R16 + X/Y8 + d16-32 + temps).
// 16 visits, 8 iterations of 2 visits; DEPTH=2 marching buffers X/Y.
__global__ __launch_bounds__(256, 4) void dens_mfma_kernel(
    const float* __restrict__ pc,     // [N,3] pointcloud
    const char*  __restrict__ wsA,    // packed A planes ((visits+DEPTH)*STREAMS tiles)
    int* __restrict__ out,            // [N] counts (pre-zeroed)
    int N, int iters, int p1off, int visits)
{
    const int lane = threadIdx.x & 63;
    const int w    = threadIdx.x >> 6;   // wave 0..3
    const int n    = lane & 31;          // output col within 32-tile = i
    const int half = lane >> 5;          // k-chunk 0/1

    const int ibase = blockIdx.x * TI;
    bf16x8 B0, B1, B2, B3;
    make_bfrag(pc, ibase + n,      N, half, B0);
    make_bfrag(pc, ibase + 32 + n, N, half, B1);
    make_bfrag(pc, ibase + 64 + n, N, half, B2);
    make_bfrag(pc, ibase + 96 + n, N, half, B3);

    // per-group column masks for the i8 reduction B operand: lane covers
    // output col (lane&31); group g owns cols 8g..8g+7 of the shared acc.
    const int gsel = n >> 3;
    const int m0 = (gsel == 0) ? 0x01010101 : 0;
    const int m1 = (gsel == 1) ? 0x01010101 : 0;
    const int m2 = (gsel == 2) ? 0x01010101 : 0;
    const int m3 = (gsel == 3) ? 0x01010101 : 0;
    const int32x4 R0 = {m0, m0, m0, m0};
    const int32x4 R1 = {m1, m1, m1, m1};
    const int32x4 R2 = {m2, m2, m2, m2};
    const int32x4 R3 = {m3, m3, m3, m3};

    const int stream = blockIdx.y * 4 + w;          // 0..51
    // marching A-plane pointer; tile stride 0x6800 B = 1664 uint4
    const uint4* __restrict__ ap = (const uint4*)
        (wsA + (half ? p1off : 0) + n * 16 + (size_t)stream * 512);
    const int T4 = 0x6800 / 16;

    const f32x16  z   = {0.f};      // zero C operand, held in regs
    int32x16      acc = {0};        // persistent i32 accumulator

    uint4 X = ap[0];
    uint4 Y = ap[T4];
    int nextoff = 2 * T4;

#define GROUPV(AV, BV, RV) { \
        f32x16 d = __builtin_amdgcn_mfma_f32_32x32x16_bf16(AV, BV, z, 0, 0, 0); \
        acc = red_group(d, RV, acc); }

    for (int t = 0; t < iters; ++t) {
        {   // visit A: consume X, refill X two tiles ahead
            const bf16x8 a = __builtin_bit_cast(bf16x8, X);
            GROUPV(a, B0, R0)
            GROUPV(a, B1, R1)
            GROUPV(a, B2, R2)
            GROUPV(a, B3, R3)
            X = ap[nextoff]; nextoff += T4;
        }
        {   // visit B: consume Y, refill Y
            const bf16x8 a = __builtin_bit_cast(bf16x8, Y);
            GROUPV(a, B0, R0)
            GROUPV(a, B1, R1)
            GROUPV(a, B2, R2)
            GROUPV(a, B3, R3)
            Y = ap[nextoff]; nextoff += T4;
        }
    }
#undef GROUPV

    // acc D-layout (32x32 i32): col = lane&31 (group g = col>>3, value
    // replicated across the 8 cols of its range), row = (q&3)+8*(q>>2)+4*half
    // = local i. acc = -128 * (#not-within) over this wave's 32*visits j's
    // -> per-i count for this wave = 32*visits + (acc >> 7).
    const int base = 32 * visits;
    __shared__ int red[4][TI];
    if ((lane & 7) == 0) {                       // one writer per (group,half)
        const int g   = n >> 3;
        const int hi4 = half << 2;               // +4 rows for upper lane-half
        int* rw = &red[w][32 * g];
        rw[ 0 + hi4] = base + (acc[0]  >> 7);
        rw[ 1 + hi4] = base + (acc[1]  >> 7);
        rw[ 2 + hi4] = base + (acc[2]  >> 7);
        rw[ 3 + hi4] = base + (acc[3]  >> 7);
        rw[ 8 + hi4] = base + (acc[4]  >> 7);
        rw[ 9 + hi4] = base + (acc[5]  >> 7);
        rw[10 + hi4] = base + (acc[6]  >> 7);
        rw[11 + hi4] = base + (acc[7]  >> 7);
        rw[16 + hi4] = base + (acc[8]  >> 7);
        rw[17 + hi4] = base + (acc[9]  >> 7);
        rw[18 + hi4] = base + (acc[10] >> 7);
        rw[19 + hi4] = base + (acc[11] >> 7);
        rw[24 + hi4] = base + (acc[12] >> 7);
        rw[25 + hi4] = base + (acc[13] >> 7);
        rw[26 + hi4] = base + (acc[14] >> 7);
        rw[27 + hi4] = base + (acc[15] >> 7);
    }
    __syncthreads();
    if (threadIdx.x < TI) {
        const int ii = ibase + threadIdx.x;
        if (ii < N) {
            const int s = red[0][threadIdx.x] + red[1][threadIdx.x] +
                          red[2][threadIdx.x] + red[3][threadIdx.x];
            atomicAdd(&out[ii], s);
        }
    }
}

extern "C" void kernel_launch(void* const* d_in, const int* in_sizes, int n_in,
                              void* d_out, int out_size, void* d_ws, size_t ws_size,
                              hipStream_t stream) {
    const float* pc  = (const float*)d_in[0];   // [N,3] pointcloud
    const float* pad = (const float*)d_in[1];   // [M,3] pointcloud_padding
    int* out = (int*)d_out;

    const int N = in_sizes[0] / 3;              // 20000
    const int M = in_sizes[1] / 3;              // 25000
    const int jt = (M + 31) / 32;               // 782 j-tiles
    int visits = (jt + STREAMS - 1) / STREAMS;  // 16
    if (visits & 1) visits++;                   // 2-visit unrolled body
    const int jtp  = (visits + DEPTH) * STREAMS;    // 936 tiles incl. prefetch overrun
    const int mtot = jtp * 32;                  // 29952 rows (~958 KB in ws)

    dens_pack_kernel<<<(mtot + 255) / 256, 256, 0, stream>>>(
        pad, (uint4*)d_ws, out, M, mtot, N);

    dim3 grid((N + TI - 1) / TI, JS);           // 157 x 13
    dens_mfma_kernel<<<grid, 256, 0, stream>>>(
        pc, (const char*)d_ws, out, N, visits / 2, mtot * 16, visits);
}